// Round 4
// baseline (678.925 us; speedup 1.0000x reference)
//
#include <hip/hip_runtime.h>
#include <stdint.h>

// ---------------------------------------------------------------------------
// SemanticMemoryModule: out = softmax((H@Wp + bp) @ C^T) @ C @ Wo + bo
// fp32 operands -> bf16 hi/lo planes; 3 cross terms folded into one K=6144
// GEMM via block-uniform k remaps:
//   A planes [Xh,Xh,Xl]: kA = k<2048 ? k : k-2048   (layout [Xh|Xl], lda 4096)
//   B planes [Yh,Yl,Yh]: kB = k<4096 ? k : k-4096   (layout [Yh|Yl], ldb 4096)
//
// R9: gemm256 K-loop restructured to the m201 8-phase schedule (4 phases per
// K-tile, 2 barriers/phase): R3's coarse {24 ds_read -> 64 MFMA} block
// serialized the LDS-read burst (~2300cy/CU) against the MFMA burst
// (~2480cy/CU) -> 42% MfmaUtil. Per-phase now: {8 ds_read_b128, [stage],
// s_barrier, lgkmcnt(0), setprio(1), 16 MFMA, setprio(0), s_barrier}.
// Staggered lgkm-drain puts early waves in MFMA while late waves' reads
// drain (T5 role-split). All 8 stage gll16 of tile t+1 issue in phase 1;
// their vmcnt(0) at end of phase 4 (~2500cy later) is effectively free.
// sched_barrier(0) pins every phase boundary (rule #18).
// Everything else unchanged from R3 (verified absmax 0.03125):
//  - 256x256 tile, 8 waves, BK=64, LDS 128KB dbuf, linear gll16 dest +
//    inverse-swizzled global source (chunk ^= row&7), swizzled ds_reads.
//  - H2 in d_out, prepass GEMMs 128-tile split-K, sb bias in softmax.
// ws: CWT 4MB | sb 64KB | WpC2 8MB | sp cr*4KB  (cr=16384 -> 76.07MB).
// ---------------------------------------------------------------------------

typedef unsigned short ushort_t;
typedef __bf16 bf16x8  __attribute__((ext_vector_type(8)));
typedef short  shortx8 __attribute__((ext_vector_type(8)));
typedef short  shortx4 __attribute__((ext_vector_type(4)));
typedef float  floatx4 __attribute__((ext_vector_type(4)));

__device__ __forceinline__ float bf2f(ushort_t u) {
  union { unsigned u; float f; } x; x.u = ((unsigned)u) << 16; return x.f;
}
__device__ __forceinline__ ushort_t f2bf(float f) {
  union { float f; unsigned u; } x; x.f = f;
  unsigned r = x.u + 0x7FFFu + ((x.u >> 16) & 1u);   // RNE
  return (ushort_t)(r >> 16);
}

__device__ __forceinline__ void gll16(const void* g, void* l) {
  __builtin_amdgcn_global_load_lds(
      (const __attribute__((address_space(1))) void*)g,
      (__attribute__((address_space(3))) void*)l, 16, 0, 0);
}

// ---------------------------------------------------------------------------
// 256x256 tile, 8 waves, BK=64, 4-phase-per-K-tile double-buffer GEMM.
// out[M,N] = A[M,K] (x) Bt[N,K]^T, fp32 out + optional bias[col].
// ---------------------------------------------------------------------------
__device__ __forceinline__ void stage_tile256(
    const ushort_t* __restrict__ A, const ushort_t* __restrict__ Bt,
    ushort_t* ldsA, ushort_t* ldsB, int wave, int lane,
    int m0, int n0, int lda, int ldb, int Mvalid, int Nvalid, int ka, int kb)
{
  const int rsub = lane >> 3;                 // row within 8-row block
  const int csw  = ((lane & 7) ^ rsub) << 3;  // inverse-swizzled chunk (ushorts)
#pragma unroll
  for (int s = 0; s < 4; ++s) {
    const int q = wave * 4 + s;               // 8-row block index 0..31
    const int r = q * 8 + rsub;
    int gm = min(m0 + r, Mvalid - 1);
    gll16(&A[(size_t)gm * lda + ka + csw], &ldsA[q * 512]);
    int gn = min(n0 + r, Nvalid - 1);
    gll16(&Bt[(size_t)gn * ldb + kb + csw], &ldsB[q * 512]);
  }
}

__device__ __forceinline__ void mfma16(
    floatx4 (*accr)[4], const shortx8* av, const shortx8* bv)
{
#pragma unroll
  for (int i = 0; i < 4; ++i)
#pragma unroll
    for (int j = 0; j < 4; ++j)
      accr[i][j] = __builtin_amdgcn_mfma_f32_16x16x32_bf16(
          __builtin_bit_cast(bf16x8, av[i]), __builtin_bit_cast(bf16x8, bv[j]),
          accr[i][j], 0, 0, 0);
}

__device__ __forceinline__ void phase_sync() {
  __builtin_amdgcn_sched_barrier(0);
  __builtin_amdgcn_s_barrier();
  asm volatile("s_waitcnt lgkmcnt(0)" ::: "memory");
  __builtin_amdgcn_sched_barrier(0);
  __builtin_amdgcn_s_setprio(1);
}
__device__ __forceinline__ void phase_end() {
  __builtin_amdgcn_s_setprio(0);
  __builtin_amdgcn_sched_barrier(0);
  __builtin_amdgcn_s_barrier();
  __builtin_amdgcn_sched_barrier(0);
}

__global__ __launch_bounds__(512, 2) void gemm256(
    const ushort_t* __restrict__ A, const ushort_t* __restrict__ Bt,
    float* __restrict__ outp, const float* __restrict__ biasp,
    int K, int lda, int ldb, int ldo, int Mvalid, int Nvalid,
    int athr, int asub, int bthr, int bsub)
{
  __shared__ __align__(16) ushort_t lds[65536];   // 128 KB: [2][A 16K|B 16K]

  const int tid  = threadIdx.x;
  const int wave = tid >> 6;
  const int lane = tid & 63;
  const int m0 = blockIdx.x * 256;
  const int n0 = blockIdx.y * 256;
  const int wm = (wave >> 2) * 128;
  const int wn = (wave & 3) * 64;
  const int fr = lane & 15;
  const int fq = lane >> 4;
  const int NT = K >> 6;

  const int cs0 = ((fq    ) ^ (fr & 7)) << 3;  // kk=0 swizzled chunk (ushorts)
  const int cs1 = ((fq + 4) ^ (fr & 7)) << 3;  // kk=1

  // prologue: stage tile 0 into buf 0, drain, barrier
  stage_tile256(A, Bt, &lds[0], &lds[16384], wave, lane, m0, n0, lda, ldb,
                Mvalid, Nvalid, 0, 0);
  asm volatile("s_waitcnt vmcnt(0)" ::: "memory");
  __builtin_amdgcn_s_barrier();
  __builtin_amdgcn_sched_barrier(0);

  floatx4 acc[8][4] = {};

  for (int t = 0; t < NT; ++t) {
    const int p = t & 1;
    const ushort_t* Ab = &lds[p * 32768];
    const ushort_t* Bb = &lds[p * 32768 + 16384];
    shortx8 a[4], b[4];

    // ---- phase 1: b@kk0 + a[0..3]@kk0; stage tile t+1 -> buf p^1 ----
#pragma unroll
    for (int j = 0; j < 4; ++j)
      b[j] = *(const shortx8*)&Bb[(wn + j * 16 + fr) * 64 + cs0];
#pragma unroll
    for (int i = 0; i < 4; ++i)
      a[i] = *(const shortx8*)&Ab[(wm + i * 16 + fr) * 64 + cs0];
    if (t + 1 < NT) {
      int k1 = (t + 1) << 6;
      int ka = (k1 < athr) ? k1 : k1 - asub;
      int kb = (k1 < bthr) ? k1 : k1 - bsub;
      stage_tile256(A, Bt, &lds[(p ^ 1) * 32768], &lds[(p ^ 1) * 32768 + 16384],
                    wave, lane, m0, n0, lda, ldb, Mvalid, Nvalid, ka, kb);
    }
    phase_sync();
    mfma16(&acc[0], a, b);
    phase_end();

    // ---- phase 2: a[4..7]@kk0 (b persists in regs) ----
#pragma unroll
    for (int i = 0; i < 4; ++i)
      a[i] = *(const shortx8*)&Ab[(wm + (i + 4) * 16 + fr) * 64 + cs0];
    phase_sync();
    mfma16(&acc[4], a, b);
    phase_end();

    // ---- phase 3: b@kk1 + a[0..3]@kk1 ----
#pragma unroll
    for (int j = 0; j < 4; ++j)
      b[j] = *(const shortx8*)&Bb[(wn + j * 16 + fr) * 64 + cs1];
#pragma unroll
    for (int i = 0; i < 4; ++i)
      a[i] = *(const shortx8*)&Ab[(wm + i * 16 + fr) * 64 + cs1];
    phase_sync();
    mfma16(&acc[0], a, b);
    phase_end();

    // ---- phase 4: a[4..7]@kk1; vmcnt(0) (my stages, issued ~3 phases ago)
#pragma unroll
    for (int i = 0; i < 4; ++i)
      a[i] = *(const shortx8*)&Ab[(wm + (i + 4) * 16 + fr) * 64 + cs1];
    phase_sync();
    mfma16(&acc[4], a, b);
    __builtin_amdgcn_s_setprio(0);
    __builtin_amdgcn_sched_barrier(0);
    asm volatile("s_waitcnt vmcnt(0)" ::: "memory");
    __builtin_amdgcn_s_barrier();
    __builtin_amdgcn_sched_barrier(0);
  }

  // D layout: col = lane&15 (n), row = quad*4 + r (m)   [m89/m91-verified]
#pragma unroll
  for (int i = 0; i < 8; ++i) {
#pragma unroll
    for (int j = 0; j < 4; ++j) {
      int col = n0 + wn + j * 16 + fr;
      float bb = biasp ? biasp[col] : 0.0f;
#pragma unroll
      for (int r = 0; r < 4; ++r) {
        int row = m0 + wm + i * 16 + fq * 4 + r;
        outp[(size_t)row * ldo + col] = acc[i][j][r] + bb;
      }
    }
  }
}

// ---------------------------------------------------------------------------
// 128xBN reg-staged GEMM (prepass use only), split-K via blockIdx.z.
// ---------------------------------------------------------------------------
template<int BN>
__global__ __launch_bounds__(256) void gemm_bt(
    const ushort_t* __restrict__ A, const ushort_t* __restrict__ Bt,
    float* __restrict__ outp, const float* __restrict__ biasp,
    int K, int Kslice, int lda, int ldb, int ldo, size_t zstride,
    int Mvalid, int Nvalid, int athr, int asub, int bthr, int bsub)
{
  constexpr int NJ    = BN / 32;
  constexpr int BSTEP = BN / 32;
  __shared__ __align__(16) ushort_t As[128 * 64];
  __shared__ __align__(16) ushort_t Bs[BN * 64];

  const int tid  = threadIdx.x;
  const int wave = tid >> 6;
  const int lane = tid & 63;
  const int m0 = blockIdx.x * 128;
  const int n0 = blockIdx.y * BN;

  const int kbeg = blockIdx.z * Kslice;
  const int kend = min(kbeg + Kslice, K);
  float* __restrict__ out = outp + (size_t)blockIdx.z * zstride;

  const int rg = tid >> 3;
  const int ck = (tid & 7) * 8;
  const int swc = (rg & 7) << 3;

  floatx4 acc[4][NJ] = {};
  const int wm = (wave >> 1) * 64;
  const int wn = (wave & 1) * (BN / 2);
  const int fr = lane & 15;
  const int fq = lane >> 4;
  const int sw = (fr & 7) << 3;

  shortx8 ra[4], rb[BSTEP];
  {
    int ka0 = (kbeg < athr) ? kbeg : kbeg - asub;
    int kb0 = (kbeg < bthr) ? kbeg : kbeg - bsub;
#pragma unroll
    for (int s = 0; s < 4; ++s) {
      int mg = min(m0 + s * 32 + rg, Mvalid - 1);
      ra[s] = *(const shortx8*)&A[(size_t)mg * lda + ka0 + ck];
    }
#pragma unroll
    for (int s = 0; s < BSTEP; ++s) {
      int ng = min(n0 + s * 32 + rg, Nvalid - 1);
      rb[s] = *(const shortx8*)&Bt[(size_t)ng * ldb + kb0 + ck];
    }
  }

  for (int k0 = kbeg; k0 < kend; k0 += 64) {
    __syncthreads();
#pragma unroll
    for (int s = 0; s < 4; ++s)
      *(shortx8*)&As[(s * 32 + rg) * 64 + (ck ^ swc)] = ra[s];
#pragma unroll
    for (int s = 0; s < BSTEP; ++s)
      *(shortx8*)&Bs[(s * 32 + rg) * 64 + (ck ^ swc)] = rb[s];
    __syncthreads();

    int kn = k0 + 64;
    if (kn < kend) {
      int ka0 = (kn < athr) ? kn : kn - asub;
      int kb0 = (kn < bthr) ? kn : kn - bsub;
#pragma unroll
      for (int s = 0; s < 4; ++s) {
        int mg = min(m0 + s * 32 + rg, Mvalid - 1);
        ra[s] = *(const shortx8*)&A[(size_t)mg * lda + ka0 + ck];
      }
#pragma unroll
      for (int s = 0; s < BSTEP; ++s) {
        int ng = min(n0 + s * 32 + rg, Nvalid - 1);
        rb[s] = *(const shortx8*)&Bt[(size_t)ng * ldb + kb0 + ck];
      }
    }

#pragma unroll
    for (int kk = 0; kk < 2; ++kk) {
      const int cs = (kk * 32 + fq * 8) ^ sw;
      shortx8 a[4], b[NJ];
#pragma unroll
      for (int i = 0; i < 4; ++i)
        a[i] = *(const shortx8*)&As[(wm + i * 16 + fr) * 64 + cs];
#pragma unroll
      for (int j = 0; j < NJ; ++j)
        b[j] = *(const shortx8*)&Bs[(wn + j * 16 + fr) * 64 + cs];
#pragma unroll
      for (int i = 0; i < 4; ++i)
#pragma unroll
        for (int j = 0; j < NJ; ++j)
          acc[i][j] = __builtin_amdgcn_mfma_f32_16x16x32_bf16(
              __builtin_bit_cast(bf16x8, a[i]), __builtin_bit_cast(bf16x8, b[j]),
              acc[i][j], 0, 0, 0);
    }
  }

#pragma unroll
  for (int i = 0; i < 4; ++i) {
#pragma unroll
    for (int j = 0; j < NJ; ++j) {
      int col = n0 + wn + j * 16 + fr;
      float bb = biasp ? biasp[col] : 0.0f;
#pragma unroll
      for (int r = 0; r < 4; ++r) {
        int row = m0 + wm + i * 16 + fq * 4 + r;
        out[(size_t)row * ldo + col] = acc[i][j][r] + bb;
      }
    }
  }
}

// ---------------------------------------------------------------------------
// fp32 [R,Cn] -> bf16 [R,2Cn] hi|lo planes
__global__ __launch_bounds__(256) void split_hilo(
    const float* __restrict__ in, ushort_t* __restrict__ out, int R, int Cn)
{
  int total4 = R * (Cn >> 2);
  for (int i = blockIdx.x * 256 + threadIdx.x; i < total4; i += gridDim.x * 256) {
    int r = i / (Cn >> 2);
    int j = (i - r * (Cn >> 2)) * 4;
    floatx4 v = *(const floatx4*)&in[(size_t)r * Cn + j];
    shortx4 hi, lo;
#pragma unroll
    for (int t = 0; t < 4; ++t) {
      ushort_t h = f2bf(v[t]);
      hi[t] = (short)h;
      lo[t] = (short)f2bf(v[t] - bf2f(h));
    }
    *(shortx4*)&out[(size_t)r * 2 * Cn + j] = hi;
    *(shortx4*)&out[(size_t)r * 2 * Cn + Cn + j] = lo;
  }
}

// Wo fp32 [2048,2048] -> WoT2 bf16 [2048, 4096] = [Wo^T hi | Wo^T lo]
__global__ __launch_bounds__(256) void transpose_split(
    const float* __restrict__ in, ushort_t* __restrict__ out)
{
  __shared__ float t[32][33];
  int bx = blockIdx.x * 32, by = blockIdx.y * 32;
  int x = threadIdx.x;
  for (int i = threadIdx.y; i < 32; i += 8)
    t[i][x] = in[(size_t)(by + i) * 2048 + bx + x];
  __syncthreads();
  for (int i = threadIdx.y; i < 32; i += 8) {
    float v = t[x][i];
    ushort_t h = f2bf(v);
    out[(size_t)(bx + i) * 4096 + (by + x)] = h;
    out[(size_t)(bx + i) * 4096 + 2048 + (by + x)] = f2bf(v - bf2f(h));
  }
}

__global__ __launch_bounds__(256) void build_sb(
    const float* __restrict__ bproj, const float* __restrict__ Cc,
    float* __restrict__ sb)
{
  int c = blockIdx.x;
  int cc = min(c, 999);
  float s = 0.f;
  for (int e = threadIdx.x; e < 2048; e += 256)
    s += bproj[e] * Cc[(size_t)cc * 2048 + e];
#pragma unroll
  for (int o = 32; o > 0; o >>= 1) s += __shfl_down(s, o, 64);
  __shared__ float red[4];
  int wave = threadIdx.x >> 6, lane = threadIdx.x & 63;
  if (lane == 0) red[wave] = s;
  __syncthreads();
  if (threadIdx.x == 0) sb[c] = red[0] + red[1] + red[2] + red[3];
}

// 4 fp32 split-K planes [R,C] -> bf16 hi|lo [R, 2C]   (WpC2 finalize)
__global__ __launch_bounds__(256) void reduce_hilo(
    const float* __restrict__ in, size_t plane, ushort_t* __restrict__ out,
    int R, int C)
{
  int total4 = R * (C >> 2);
  for (int i = blockIdx.x * 256 + threadIdx.x; i < total4; i += gridDim.x * 256) {
    int r = i / (C >> 2);
    int j = (i - r * (C >> 2)) * 4;
    size_t idx = (size_t)r * C + j;
    floatx4 v = *(const floatx4*)&in[idx];
#pragma unroll
    for (int p = 1; p < 4; ++p)
      v += *(const floatx4*)&in[p * plane + idx];
    shortx4 hi, lo;
#pragma unroll
    for (int t = 0; t < 4; ++t) {
      ushort_t h = f2bf(v[t]);
      hi[t] = (short)h;
      lo[t] = (short)f2bf(v[t] - bf2f(h));
    }
    *(shortx4*)&out[(size_t)r * 2 * C + j] = hi;
    *(shortx4*)&out[(size_t)r * 2 * C + C + j] = lo;
  }
}

// 4 fp32 split-K planes -> bf16 (flat)   (CWT finalize)
__global__ __launch_bounds__(256) void reduce_bf16(
    const float* __restrict__ in, size_t plane, ushort_t* __restrict__ out,
    int total)
{
  int total4 = total >> 2;
  for (int i = blockIdx.x * 256 + threadIdx.x; i < total4; i += gridDim.x * 256) {
    size_t j = (size_t)i * 4;
    floatx4 v = *(const floatx4*)&in[j];
#pragma unroll
    for (int p = 1; p < 4; ++p)
      v += *(const floatx4*)&in[p * plane + j];
    shortx4 o;
#pragma unroll
    for (int t = 0; t < 4; ++t) o[t] = (short)f2bf(v[t]);
    *(shortx4*)&out[j] = o;
  }
}

// fp32 scores row [1024] + sb bias -> bf16 probs row in-place (first 2KB).
__global__ __launch_bounds__(256) void softmax_k(
    void* buf, const float* __restrict__ sb)
{
  int row = blockIdx.x;
  const float* s = (const float*)buf + (size_t)row * 1024;
  ushort_t*    p = (ushort_t*)buf + (size_t)row * 2048;
  int t = threadIdx.x;
  float v[4];
#pragma unroll
  for (int i = 0; i < 4; ++i) {
    int c = t + i * 256;
    float x = (c < 1000) ? s[c] + sb[c] : -3.0e38f;
    v[i] = (x == x) ? x : -3.0e38f;
  }
  float m = fmaxf(fmaxf(v[0], v[1]), fmaxf(v[2], v[3]));
#pragma unroll
  for (int o = 32; o > 0; o >>= 1) m = fmaxf(m, __shfl_xor(m, o, 64));
  __shared__ float redm[4], reds[4];
  int wave = t >> 6, lane = t & 63;
  if (lane == 0) redm[wave] = m;
  __syncthreads();
  m = fmaxf(fmaxf(redm[0], redm[1]), fmaxf(redm[2], redm[3]));
  float pv[4]; float sum = 0.f;
#pragma unroll
  for (int i = 0; i < 4; ++i) {
    int c = t + i * 256;
    pv[i] = (c < 1000) ? __expf(v[i] - m) : 0.f;
    sum += pv[i];
  }
#pragma unroll
  for (int o = 32; o > 0; o >>= 1) sum += __shfl_xor(sum, o, 64);
  if (lane == 0) reds[wave] = sum;
  __syncthreads();
  sum = reds[0] + reds[1] + reds[2] + reds[3];
  float inv = (sum > 0.f) ? 1.0f / sum : 0.f;
#pragma unroll
  for (int i = 0; i < 4; ++i) {
    int c = t + i * 256;
    p[c] = f2bf(pv[i] * inv);
  }
}

// ---------------------------------------------------------------------------
extern "C" void kernel_launch(void* const* d_in, const int* in_sizes, int n_in,
                              void* d_out, int out_size, void* d_ws, size_t ws_size,
                              hipStream_t stream)
{
  const float* H   = (const float*)d_in[0];  // [16384, 2048] fp32
  const float* Cc  = (const float*)d_in[1];  // [1000, 2048]  fp32
  const float* Wp  = (const float*)d_in[2];  // [2048, 2048]  fp32
  const float* bpj = (const float*)d_in[3];  // [2048]        fp32
  const float* Wo  = (const float*)d_in[4];  // [2048, 2048]  fp32
  const float* bo  = (const float*)d_in[5];  // [2048]        fp32
  float* out = (float*)d_out;                // [16384, 2048] fp32 (128MB)

  const size_t MB = (size_t)1 << 20;
  char* ws = (char*)d_ws;

  // persistent ws: CWT 4MB | sb 64KB | WpC2 8MB | sp (scores, cr*4KB)
  ushort_t* CWT  = (ushort_t*)ws;
  float*    sb   = (float*)(ws + 4 * MB);
  ushort_t* WpC2 = (ushort_t*)(ws + 4 * MB + 65536);
  const size_t base2 = 12 * MB + 65536;

  // chunk rows: largest cr with base2 + cr*4KB <= ws_size (floor 256 for
  // the 256-row tiles of gemm256).
  int cr = 256;
  for (int c = 16384; c >= 256; c >>= 1)
    if (ws_size >= base2 + (size_t)c * 4096) { cr = c; break; }
  float* sp = (float*)(ws + base2);          // [cr,1024] fp32 / probs bf16

  // d_out scratch (all consumed before split_hilo(H) overwrites d_out):
  char* ob = (char*)d_out;
  ushort_t* C2   = (ushort_t*)ob;              // [1000 x 4096] bf16, ~7.8MB
  ushort_t* Wp2  = (ushort_t*)(ob + 8 * MB);   // [2048 x 4096] bf16, 16MB
  ushort_t* WoT2 = (ushort_t*)(ob + 24 * MB);  // [2048 x 4096] bf16, 16MB
  float*    pp   = (float*)(ob + 40 * MB);     // split-K partials, 32MB (ends 72MB)

  // --- prepasses ---
  split_hilo<<<dim3(2048), dim3(256), 0, stream>>>(Cc, C2, 1000, 2048);
  split_hilo<<<dim3(4096), dim3(256), 0, stream>>>(Wp, Wp2, 2048, 2048);
  transpose_split<<<dim3(64, 64), dim3(32, 8), 0, stream>>>(Wo, WoT2);
  build_sb<<<dim3(1024), dim3(256), 0, stream>>>(bpj, Cc, sb);
  // WpC2 = C @ Wp^T planes: split-K=4 -> 4 fp32 planes [1024,2048] in pp.
  gemm_bt<64><<<dim3(8, 32, 4), dim3(256), 0, stream>>>(
      C2, Wp2, pp, nullptr, 6144, 1536, 4096, 4096, 2048, (size_t)1024 * 2048,
      1000, 2048, 2048, 2048, 4096, 4096);
  reduce_hilo<<<dim3(2048), dim3(256), 0, stream>>>(
      pp, (size_t)1024 * 2048, WpC2, 1024, 2048);
  // CWT = (C @ Wo)^T: split-K=4.
  gemm_bt<64><<<dim3(16, 16, 4), dim3(256), 0, stream>>>(
      WoT2, C2, pp, nullptr, 6144, 1536, 4096, 4096, 1024, (size_t)2048 * 1024,
      2048, 1000, 2048, 2048, 4096, 4096);
  reduce_bf16<<<dim3(2048), dim3(256), 0, stream>>>(
      pp, (size_t)2048 * 1024, CWT, 2048 * 1024);

  // H2 (full) lives in d_out: H2 row r == out row r bytes (8KB each).
  split_hilo<<<dim3(8192), dim3(256), 0, stream>>>(H, (ushort_t*)ob, 16384, 2048);

  // --- chunked main loop ---
  const int nc = 16384 / cr;
  for (int c = 0; c < nc; ++c) {
    const ushort_t* H2c = (const ushort_t*)ob + (size_t)c * cr * 4096;
    float* outc = out + (size_t)c * cr * 2048;
    // scores: A=H2(Hh,Hh,Hl), B=WpC2(Wh,Wl,Wh), K=6144, fp32 (bias in softmax)
    gemm256<<<dim3(cr / 256, 4), dim3(512), 0, stream>>>(
        H2c, WpC2, sp, nullptr, 6144, 4096, 4096, 1024,
        cr, 1024, 2048, 2048, 4096, 4096);
    softmax_k<<<dim3(cr), dim3(256), 0, stream>>>(sp, sb);
    // out: A=probs bf16 (lda 2048 in-place), B=CWT, K=1024, fp32 out + bo
    gemm256<<<dim3(cr / 256, 8), dim3(512), 0, stream>>>(
        (const ushort_t*)sp, CWT, outc, bo, 1024, 2048, 1024, 2048,
        cr, 2048, 1 << 30, 0, 1 << 30, 0);
  }
}

// Round 5
// 627.922 us; speedup vs baseline: 1.0812x; 1.0812x over previous
//
#include <hip/hip_runtime.h>
#include <stdint.h>

// ---------------------------------------------------------------------------
// SemanticMemoryModule: out = softmax((H@Wp + bp) @ C^T) @ C @ Wo + bo
// fp32 operands -> bf16 hi/lo planes; 3 cross terms folded into one K=6144
// GEMM via block-uniform k remaps:
//   A planes [Xh,Xh,Xl]: kA = k<2048 ? k : k-2048   (layout [Xh|Xl], lda 4096)
//   B planes [Yh,Yl,Yh]: kB = k<4096 ? k : k-4096   (layout [Yh|Yl], ldb 4096)
//
// R10: drop R9's lockstep per-phase barriers (they SERIALIZED the LDS-read
// burst (~2300cy/CU/K-tile) against the MFMA burst (~2480cy) -> 44% MfmaUtil
// = 2480/5500 measured). New gemm256 K-loop: per-WAVE software pipeline,
// reads for MFMA-group g+1 issue BEFORE group g's MFMAs (named frag sets,
// sched_barrier(0)-pinned sections; compiler auto-emits counted lgkmcnt).
// ONE barrier per K-tile (dbuf swap) preceded by per-wave vmcnt(0) (free:
// the 16 gll16 stages were issued ~3 groups earlier). Staging addresses
// hoisted to 8 persistent pointers (VALUBusy 20% -> ~13%).
// Unchanged from R9 (verified absmax 0.03125):
//  - 256x256 tile, 8 waves (2Mx4N), BK=64, LDS 128KB dbuf, linear gll16
//    dest + inverse-swizzled global source (chunk ^= row&7), swizzled
//    ds_read_b128 (0 bank conflicts), setprio(1) around MFMA clusters.
//  - H2 in d_out, prepass GEMMs 128-tile split-K, sb bias in softmax.
// ws: CWT 4MB | sb 64KB | WpC2 8MB | sp cr*4KB  (cr=16384 -> 76.07MB).
// ---------------------------------------------------------------------------

typedef unsigned short ushort_t;
typedef __bf16 bf16x8  __attribute__((ext_vector_type(8)));
typedef short  shortx8 __attribute__((ext_vector_type(8)));
typedef short  shortx4 __attribute__((ext_vector_type(4)));
typedef float  floatx4 __attribute__((ext_vector_type(4)));

__device__ __forceinline__ float bf2f(ushort_t u) {
  union { unsigned u; float f; } x; x.u = ((unsigned)u) << 16; return x.f;
}
__device__ __forceinline__ ushort_t f2bf(float f) {
  union { float f; unsigned u; } x; x.f = f;
  unsigned r = x.u + 0x7FFFu + ((x.u >> 16) & 1u);   // RNE
  return (ushort_t)(r >> 16);
}

__device__ __forceinline__ void gll16(const void* g, void* l) {
  __builtin_amdgcn_global_load_lds(
      (const __attribute__((address_space(1))) void*)g,
      (__attribute__((address_space(3))) void*)l, 16, 0, 0);
}

__device__ __forceinline__ void mfma16(
    floatx4 (*accr)[4], const shortx8* av, const shortx8* bv)
{
#pragma unroll
  for (int i = 0; i < 4; ++i)
#pragma unroll
    for (int j = 0; j < 4; ++j)
      accr[i][j] = __builtin_amdgcn_mfma_f32_16x16x32_bf16(
          __builtin_bit_cast(bf16x8, av[i]), __builtin_bit_cast(bf16x8, bv[j]),
          accr[i][j], 0, 0, 0);
}

// ---------------------------------------------------------------------------
// 256x256 tile, 8 waves, BK=64, per-wave-pipelined double-buffer GEMM.
// out[M,N] = A[M,K] (x) Bt[N,K]^T, fp32 out + optional bias[col].
// ---------------------------------------------------------------------------
__global__ __launch_bounds__(512, 2) void gemm256(
    const ushort_t* __restrict__ A, const ushort_t* __restrict__ Bt,
    float* __restrict__ outp, const float* __restrict__ biasp,
    int K, int lda, int ldb, int ldo, int Mvalid, int Nvalid,
    int athr, int asub, int bthr, int bsub)
{
  __shared__ __align__(16) ushort_t lds[65536];   // 128 KB: [2][A 16K|B 16K]

  const int tid  = threadIdx.x;
  const int wave = tid >> 6;
  const int lane = tid & 63;
  const int m0 = blockIdx.x * 256;
  const int n0 = blockIdx.y * 256;
  const int wm = (wave >> 2) * 128;
  const int wn = (wave & 3) * 64;
  const int fr = lane & 15;
  const int fq = lane >> 4;
  const int NT = K >> 6;

  const int cs0 = ((fq    ) ^ (fr & 7)) << 3;  // kk=0 swizzled chunk (ushorts)
  const int cs1 = ((fq + 4) ^ (fr & 7)) << 3;  // kk=1

  // loop-invariant staging addresses (hoisted: min + row-mul done ONCE)
  const int rsub = lane >> 3;
  const int csw  = ((lane & 7) ^ rsub) << 3;   // inverse-swizzled chunk
  const ushort_t* Ag[4]; const ushort_t* Bg[4]; int dOff[4];
#pragma unroll
  for (int s = 0; s < 4; ++s) {
    const int q = wave * 4 + s;                // 8-row block index 0..31
    const int r = q * 8 + rsub;
    Ag[s] = A  + (size_t)min(m0 + r, Mvalid - 1) * lda + csw;
    Bg[s] = Bt + (size_t)min(n0 + r, Nvalid - 1) * ldb + csw;
    dOff[s] = q * 512;                         // linear LDS dest (ushorts)
  }

  // prologue: stage tile 0 into buf 0, publish
#pragma unroll
  for (int s = 0; s < 4; ++s) gll16(Ag[s], &lds[dOff[s]]);
#pragma unroll
  for (int s = 0; s < 4; ++s) gll16(Bg[s], &lds[16384 + dOff[s]]);
  asm volatile("s_waitcnt vmcnt(0)" ::: "memory");
  __builtin_amdgcn_s_barrier();
  __builtin_amdgcn_sched_barrier(0);

  floatx4 acc[8][4] = {};

  for (int t = 0; t < NT; ++t) {
    const int p = t & 1;
    const ushort_t* Ab = &lds[p * 32768];
    const ushort_t* Bb = &lds[p * 32768 + 16384];
    ushort_t* Sa = &lds[(p ^ 1) * 32768];
    ushort_t* Sb = Sa + 16384;

    shortx8 bX[4], bY[4], a1[4], a2[4], a3[4], a4[4];

    // R0: b@kk0 + a[0..3]@kk0  (8 ds_read_b128)
#pragma unroll
    for (int j = 0; j < 4; ++j)
      bX[j] = *(const shortx8*)&Bb[(wn + j * 16 + fr) * 64 + cs0];
#pragma unroll
    for (int i = 0; i < 4; ++i)
      a1[i] = *(const shortx8*)&Ab[(wm + i * 16 + fr) * 64 + cs0];
    // R1: a[4..7]@kk0 ; stage tile t+1 -> buf p^1 (vmcnt only, no lgkm)
#pragma unroll
    for (int i = 0; i < 4; ++i)
      a2[i] = *(const shortx8*)&Ab[(wm + (i + 4) * 16 + fr) * 64 + cs0];
    if (t + 1 < NT) {
      int k1 = (t + 1) << 6;
      int ka = (k1 < athr) ? k1 : k1 - asub;
      int kb = (k1 < bthr) ? k1 : k1 - bsub;
#pragma unroll
      for (int s = 0; s < 4; ++s) gll16(Ag[s] + ka, &Sa[dOff[s]]);
#pragma unroll
      for (int s = 0; s < 4; ++s) gll16(Bg[s] + kb, &Sb[dOff[s]]);
    }
    __builtin_amdgcn_sched_barrier(0);
    // G0: needs bX,a1 (compiler emits lgkmcnt(4): a2 still in flight)
    __builtin_amdgcn_s_setprio(1);
    mfma16(&acc[0], a1, bX);
    __builtin_amdgcn_s_setprio(0);
    __builtin_amdgcn_sched_barrier(0);
    // R2: b@kk1 + a[0..3]@kk1 (issue while G1 runs next)
#pragma unroll
    for (int j = 0; j < 4; ++j)
      bY[j] = *(const shortx8*)&Bb[(wn + j * 16 + fr) * 64 + cs1];
#pragma unroll
    for (int i = 0; i < 4; ++i)
      a3[i] = *(const shortx8*)&Ab[(wm + i * 16 + fr) * 64 + cs1];
    __builtin_amdgcn_sched_barrier(0);
    // G1: needs a2,bX (lgkmcnt(8): bY,a3 in flight)
    __builtin_amdgcn_s_setprio(1);
    mfma16(&acc[4], a2, bX);
    __builtin_amdgcn_s_setprio(0);
    __builtin_amdgcn_sched_barrier(0);
    // R3: a[4..7]@kk1
#pragma unroll
    for (int i = 0; i < 4; ++i)
      a4[i] = *(const shortx8*)&Ab[(wm + (i + 4) * 16 + fr) * 64 + cs1];
    __builtin_amdgcn_sched_barrier(0);
    // G2: needs bY,a3 (lgkmcnt(4): a4 in flight)
    __builtin_amdgcn_s_setprio(1);
    mfma16(&acc[0], a3, bY);
    __builtin_amdgcn_s_setprio(0);
    __builtin_amdgcn_sched_barrier(0);
    // G3: needs a4 (lgkmcnt(0))
    __builtin_amdgcn_s_setprio(1);
    mfma16(&acc[4], a4, bY);
    __builtin_amdgcn_s_setprio(0);
    __builtin_amdgcn_sched_barrier(0);
    // dbuf swap: own stages landed (issued ~3 groups ago -> free wait);
    // barrier publishes all waves' stages.
    asm volatile("s_waitcnt vmcnt(0)" ::: "memory");
    __builtin_amdgcn_s_barrier();
    __builtin_amdgcn_sched_barrier(0);
  }

  // D layout: col = lane&15 (n), row = quad*4 + r (m)   [m89/m91-verified]
#pragma unroll
  for (int i = 0; i < 8; ++i) {
#pragma unroll
    for (int j = 0; j < 4; ++j) {
      int col = n0 + wn + j * 16 + fr;
      float bb = biasp ? biasp[col] : 0.0f;
#pragma unroll
      for (int r = 0; r < 4; ++r) {
        int row = m0 + wm + i * 16 + fq * 4 + r;
        outp[(size_t)row * ldo + col] = acc[i][j][r] + bb;
      }
    }
  }
}

// ---------------------------------------------------------------------------
// 128xBN reg-staged GEMM (prepass use only), split-K via blockIdx.z.
// ---------------------------------------------------------------------------
template<int BN>
__global__ __launch_bounds__(256) void gemm_bt(
    const ushort_t* __restrict__ A, const ushort_t* __restrict__ Bt,
    float* __restrict__ outp, const float* __restrict__ biasp,
    int K, int Kslice, int lda, int ldb, int ldo, size_t zstride,
    int Mvalid, int Nvalid, int athr, int asub, int bthr, int bsub)
{
  constexpr int NJ    = BN / 32;
  constexpr int BSTEP = BN / 32;
  __shared__ __align__(16) ushort_t As[128 * 64];
  __shared__ __align__(16) ushort_t Bs[BN * 64];

  const int tid  = threadIdx.x;
  const int wave = tid >> 6;
  const int lane = tid & 63;
  const int m0 = blockIdx.x * 128;
  const int n0 = blockIdx.y * BN;

  const int kbeg = blockIdx.z * Kslice;
  const int kend = min(kbeg + Kslice, K);
  float* __restrict__ out = outp + (size_t)blockIdx.z * zstride;

  const int rg = tid >> 3;
  const int ck = (tid & 7) * 8;
  const int swc = (rg & 7) << 3;

  floatx4 acc[4][NJ] = {};
  const int wm = (wave >> 1) * 64;
  const int wn = (wave & 1) * (BN / 2);
  const int fr = lane & 15;
  const int fq = lane >> 4;
  const int sw = (fr & 7) << 3;

  shortx8 ra[4], rb[BSTEP];
  {
    int ka0 = (kbeg < athr) ? kbeg : kbeg - asub;
    int kb0 = (kbeg < bthr) ? kbeg : kbeg - bsub;
#pragma unroll
    for (int s = 0; s < 4; ++s) {
      int mg = min(m0 + s * 32 + rg, Mvalid - 1);
      ra[s] = *(const shortx8*)&A[(size_t)mg * lda + ka0 + ck];
    }
#pragma unroll
    for (int s = 0; s < BSTEP; ++s) {
      int ng = min(n0 + s * 32 + rg, Nvalid - 1);
      rb[s] = *(const shortx8*)&Bt[(size_t)ng * ldb + kb0 + ck];
    }
  }

  for (int k0 = kbeg; k0 < kend; k0 += 64) {
    __syncthreads();
#pragma unroll
    for (int s = 0; s < 4; ++s)
      *(shortx8*)&As[(s * 32 + rg) * 64 + (ck ^ swc)] = ra[s];
#pragma unroll
    for (int s = 0; s < BSTEP; ++s)
      *(shortx8*)&Bs[(s * 32 + rg) * 64 + (ck ^ swc)] = rb[s];
    __syncthreads();

    int kn = k0 + 64;
    if (kn < kend) {
      int ka0 = (kn < athr) ? kn : kn - asub;
      int kb0 = (kn < bthr) ? kn : kn - bsub;
#pragma unroll
      for (int s = 0; s < 4; ++s) {
        int mg = min(m0 + s * 32 + rg, Mvalid - 1);
        ra[s] = *(const shortx8*)&A[(size_t)mg * lda + ka0 + ck];
      }
#pragma unroll
      for (int s = 0; s < BSTEP; ++s) {
        int ng = min(n0 + s * 32 + rg, Nvalid - 1);
        rb[s] = *(const shortx8*)&Bt[(size_t)ng * ldb + kb0 + ck];
      }
    }

#pragma unroll
    for (int kk = 0; kk < 2; ++kk) {
      const int cs = (kk * 32 + fq * 8) ^ sw;
      shortx8 a[4], b[NJ];
#pragma unroll
      for (int i = 0; i < 4; ++i)
        a[i] = *(const shortx8*)&As[(wm + i * 16 + fr) * 64 + cs];
#pragma unroll
      for (int j = 0; j < NJ; ++j)
        b[j] = *(const shortx8*)&Bs[(wn + j * 16 + fr) * 64 + cs];
#pragma unroll
      for (int i = 0; i < 4; ++i)
#pragma unroll
        for (int j = 0; j < NJ; ++j)
          acc[i][j] = __builtin_amdgcn_mfma_f32_16x16x32_bf16(
              __builtin_bit_cast(bf16x8, a[i]), __builtin_bit_cast(bf16x8, b[j]),
              acc[i][j], 0, 0, 0);
    }
  }

#pragma unroll
  for (int i = 0; i < 4; ++i) {
#pragma unroll
    for (int j = 0; j < NJ; ++j) {
      int col = n0 + wn + j * 16 + fr;
      float bb = biasp ? biasp[col] : 0.0f;
#pragma unroll
      for (int r = 0; r < 4; ++r) {
        int row = m0 + wm + i * 16 + fq * 4 + r;
        out[(size_t)row * ldo + col] = acc[i][j][r] + bb;
      }
    }
  }
}

// ---------------------------------------------------------------------------
// fp32 [R,Cn] -> bf16 [R,2Cn] hi|lo planes
__global__ __launch_bounds__(256) void split_hilo(
    const float* __restrict__ in, ushort_t* __restrict__ out, int R, int Cn)
{
  int total4 = R * (Cn >> 2);
  for (int i = blockIdx.x * 256 + threadIdx.x; i < total4; i += gridDim.x * 256) {
    int r = i / (Cn >> 2);
    int j = (i - r * (Cn >> 2)) * 4;
    floatx4 v = *(const floatx4*)&in[(size_t)r * Cn + j];
    shortx4 hi, lo;
#pragma unroll
    for (int t = 0; t < 4; ++t) {
      ushort_t h = f2bf(v[t]);
      hi[t] = (short)h;
      lo[t] = (short)f2bf(v[t] - bf2f(h));
    }
    *(shortx4*)&out[(size_t)r * 2 * Cn + j] = hi;
    *(shortx4*)&out[(size_t)r * 2 * Cn + Cn + j] = lo;
  }
}

// Wo fp32 [2048,2048] -> WoT2 bf16 [2048, 4096] = [Wo^T hi | Wo^T lo]
__global__ __launch_bounds__(256) void transpose_split(
    const float* __restrict__ in, ushort_t* __restrict__ out)
{
  __shared__ float t[32][33];
  int bx = blockIdx.x * 32, by = blockIdx.y * 32;
  int x = threadIdx.x;
  for (int i = threadIdx.y; i < 32; i += 8)
    t[i][x] = in[(size_t)(by + i) * 2048 + bx + x];
  __syncthreads();
  for (int i = threadIdx.y; i < 32; i += 8) {
    float v = t[x][i];
    ushort_t h = f2bf(v);
    out[(size_t)(bx + i) * 4096 + (by + x)] = h;
    out[(size_t)(bx + i) * 4096 + 2048 + (by + x)] = f2bf(v - bf2f(h));
  }
}

__global__ __launch_bounds__(256) void build_sb(
    const float* __restrict__ bproj, const float* __restrict__ Cc,
    float* __restrict__ sb)
{
  int c = blockIdx.x;
  int cc = min(c, 999);
  float s = 0.f;
  for (int e = threadIdx.x; e < 2048; e += 256)
    s += bproj[e] * Cc[(size_t)cc * 2048 + e];
#pragma unroll
  for (int o = 32; o > 0; o >>= 1) s += __shfl_down(s, o, 64);
  __shared__ float red[4];
  int wave = threadIdx.x >> 6, lane = threadIdx.x & 63;
  if (lane == 0) red[wave] = s;
  __syncthreads();
  if (threadIdx.x == 0) sb[c] = red[0] + red[1] + red[2] + red[3];
}

// 4 fp32 split-K planes [R,C] -> bf16 hi|lo [R, 2C]   (WpC2 finalize)
__global__ __launch_bounds__(256) void reduce_hilo(
    const float* __restrict__ in, size_t plane, ushort_t* __restrict__ out,
    int R, int C)
{
  int total4 = R * (C >> 2);
  for (int i = blockIdx.x * 256 + threadIdx.x; i < total4; i += gridDim.x * 256) {
    int r = i / (C >> 2);
    int j = (i - r * (C >> 2)) * 4;
    size_t idx = (size_t)r * C + j;
    floatx4 v = *(const floatx4*)&in[idx];
#pragma unroll
    for (int p = 1; p < 4; ++p)
      v += *(const floatx4*)&in[p * plane + idx];
    shortx4 hi, lo;
#pragma unroll
    for (int t = 0; t < 4; ++t) {
      ushort_t h = f2bf(v[t]);
      hi[t] = (short)h;
      lo[t] = (short)f2bf(v[t] - bf2f(h));
    }
    *(shortx4*)&out[(size_t)r * 2 * C + j] = hi;
    *(shortx4*)&out[(size_t)r * 2 * C + C + j] = lo;
  }
}

// 4 fp32 split-K planes -> bf16 (flat)   (CWT finalize)
__global__ __launch_bounds__(256) void reduce_bf16(
    const float* __restrict__ in, size_t plane, ushort_t* __restrict__ out,
    int total)
{
  int total4 = total >> 2;
  for (int i = blockIdx.x * 256 + threadIdx.x; i < total4; i += gridDim.x * 256) {
    size_t j = (size_t)i * 4;
    floatx4 v = *(const floatx4*)&in[j];
#pragma unroll
    for (int p = 1; p < 4; ++p)
      v += *(const floatx4*)&in[p * plane + j];
    shortx4 o;
#pragma unroll
    for (int t = 0; t < 4; ++t) o[t] = (short)f2bf(v[t]);
    *(shortx4*)&out[j] = o;
  }
}

// fp32 scores row [1024] + sb bias -> bf16 probs row in-place (first 2KB).
__global__ __launch_bounds__(256) void softmax_k(
    void* buf, const float* __restrict__ sb)
{
  int row = blockIdx.x;
  const float* s = (const float*)buf + (size_t)row * 1024;
  ushort_t*    p = (ushort_t*)buf + (size_t)row * 2048;
  int t = threadIdx.x;
  float v[4];
#pragma unroll
  for (int i = 0; i < 4; ++i) {
    int c = t + i * 256;
    float x = (c < 1000) ? s[c] + sb[c] : -3.0e38f;
    v[i] = (x == x) ? x : -3.0e38f;
  }
  float m = fmaxf(fmaxf(v[0], v[1]), fmaxf(v[2], v[3]));
#pragma unroll
  for (int o = 32; o > 0; o >>= 1) m = fmaxf(m, __shfl_xor(m, o, 64));
  __shared__ float redm[4], reds[4];
  int wave = t >> 6, lane = t & 63;
  if (lane == 0) redm[wave] = m;
  __syncthreads();
  m = fmaxf(fmaxf(redm[0], redm[1]), fmaxf(redm[2], redm[3]));
  float pv[4]; float sum = 0.f;
#pragma unroll
  for (int i = 0; i < 4; ++i) {
    int c = t + i * 256;
    pv[i] = (c < 1000) ? __expf(v[i] - m) : 0.f;
    sum += pv[i];
  }
#pragma unroll
  for (int o = 32; o > 0; o >>= 1) sum += __shfl_xor(sum, o, 64);
  if (lane == 0) reds[wave] = sum;
  __syncthreads();
  sum = reds[0] + reds[1] + reds[2] + reds[3];
  float inv = (sum > 0.f) ? 1.0f / sum : 0.f;
#pragma unroll
  for (int i = 0; i < 4; ++i) {
    int c = t + i * 256;
    p[c] = f2bf(pv[i] * inv);
  }
}

// ---------------------------------------------------------------------------
extern "C" void kernel_launch(void* const* d_in, const int* in_sizes, int n_in,
                              void* d_out, int out_size, void* d_ws, size_t ws_size,
                              hipStream_t stream)
{
  const float* H   = (const float*)d_in[0];  // [16384, 2048] fp32
  const float* Cc  = (const float*)d_in[1];  // [1000, 2048]  fp32
  const float* Wp  = (const float*)d_in[2];  // [2048, 2048]  fp32
  const float* bpj = (const float*)d_in[3];  // [2048]        fp32
  const float* Wo  = (const float*)d_in[4];  // [2048, 2048]  fp32
  const float* bo  = (const float*)d_in[5];  // [2048]        fp32
  float* out = (float*)d_out;                // [16384, 2048] fp32 (128MB)

  const size_t MB = (size_t)1 << 20;
  char* ws = (char*)d_ws;

  // persistent ws: CWT 4MB | sb 64KB | WpC2 8MB | sp (scores, cr*4KB)
  ushort_t* CWT  = (ushort_t*)ws;
  float*    sb   = (float*)(ws + 4 * MB);
  ushort_t* WpC2 = (ushort_t*)(ws + 4 * MB + 65536);
  const size_t base2 = 12 * MB + 65536;

  // chunk rows: largest cr with base2 + cr*4KB <= ws_size (floor 256 for
  // the 256-row tiles of gemm256).
  int cr = 256;
  for (int c = 16384; c >= 256; c >>= 1)
    if (ws_size >= base2 + (size_t)c * 4096) { cr = c; break; }
  float* sp = (float*)(ws + base2);          // [cr,1024] fp32 / probs bf16

  // d_out scratch (all consumed before split_hilo(H) overwrites d_out):
  char* ob = (char*)d_out;
  ushort_t* C2   = (ushort_t*)ob;              // [1000 x 4096] bf16, ~7.8MB
  ushort_t* Wp2  = (ushort_t*)(ob + 8 * MB);   // [2048 x 4096] bf16, 16MB
  ushort_t* WoT2 = (ushort_t*)(ob + 24 * MB);  // [2048 x 4096] bf16, 16MB
  float*    pp   = (float*)(ob + 40 * MB);     // split-K partials, 32MB (ends 72MB)

  // --- prepasses ---
  split_hilo<<<dim3(2048), dim3(256), 0, stream>>>(Cc, C2, 1000, 2048);
  split_hilo<<<dim3(4096), dim3(256), 0, stream>>>(Wp, Wp2, 2048, 2048);
  transpose_split<<<dim3(64, 64), dim3(32, 8), 0, stream>>>(Wo, WoT2);
  build_sb<<<dim3(1024), dim3(256), 0, stream>>>(bpj, Cc, sb);
  // WpC2 = C @ Wp^T planes: split-K=4 -> 4 fp32 planes [1024,2048] in pp.
  gemm_bt<64><<<dim3(8, 32, 4), dim3(256), 0, stream>>>(
      C2, Wp2, pp, nullptr, 6144, 1536, 4096, 4096, 2048, (size_t)1024 * 2048,
      1000, 2048, 2048, 2048, 4096, 4096);
  reduce_hilo<<<dim3(2048), dim3(256), 0, stream>>>(
      pp, (size_t)1024 * 2048, WpC2, 1024, 2048);
  // CWT = (C @ Wo)^T: split-K=4.
  gemm_bt<64><<<dim3(16, 16, 4), dim3(256), 0, stream>>>(
      WoT2, C2, pp, nullptr, 6144, 1536, 4096, 4096, 1024, (size_t)2048 * 1024,
      2048, 1000, 2048, 2048, 4096, 4096);
  reduce_bf16<<<dim3(2048), dim3(256), 0, stream>>>(
      pp, (size_t)2048 * 1024, CWT, 2048 * 1024);

  // H2 (full) lives in d_out: H2 row r == out row r bytes (8KB each).
  split_hilo<<<dim3(8192), dim3(256), 0, stream>>>(H, (ushort_t*)ob, 16384, 2048);

  // --- chunked main loop ---
  const int nc = 16384 / cr;
  for (int c = 0; c < nc; ++c) {
    const ushort_t* H2c = (const ushort_t*)ob + (size_t)c * cr * 4096;
    float* outc = out + (size_t)c * cr * 2048;
    // scores: A=H2(Hh,Hh,Hl), B=WpC2(Wh,Wl,Wh), K=6144, fp32 (bias in softmax)
    gemm256<<<dim3(cr / 256, 4), dim3(512), 0, stream>>>(
        H2c, WpC2, sp, nullptr, 6144, 4096, 4096, 1024,
        cr, 1024, 2048, 2048, 4096, 4096);
    softmax_k<<<dim3(cr), dim3(256), 0, stream>>>(sp, sb);
    // out: A=probs bf16 (lda 2048 in-place), B=CWT, K=1024, fp32 out + bo
    gemm256<<<dim3(cr / 256, 8), dim3(512), 0, stream>>>(
        (const ushort_t*)sp, CWT, outc, bo, 1024, 2048, 1024, 2048,
        cr, 2048, 1 << 30, 0, 1 << 30, 0);
  }
}